// Round 2
// baseline (23221.581 us; speedup 1.0000x reference)
//
#include <hip/hip_runtime.h>
#include <cstdint>

#define NWG  256
#define NTHR 512
#define HBF_SHORTS 262144ull            // one h buffer: 256*1024 bf16
#define WS_NEED    (2ull*HBF_SHORTS*2ull + 256ull)
#define BLDS_BYTES 147456               // 64 rows * 1152 K * 2B (XOR-swizzled)
#define SMEM_BYTES (BLDS_BYTES + 16384) // + zscr 64*64 f32  == 163840 == 160KiB

typedef __attribute__((ext_vector_type(8))) short  short8;
typedef __attribute__((ext_vector_type(4))) float  float4v;

__device__ __forceinline__ short bf16r(float f) {
  union { float f; uint32_t u; } v; v.f = f;
  uint32_t r = (v.u + 0x7FFFu + ((v.u >> 16) & 1u)) >> 16;   // RNE
  return (short)(uint16_t)r;
}
__device__ __forceinline__ float sig_(float x)  { return 1.f / (1.f + __expf(-x)); }
__device__ __forceinline__ float tanh_(float x) {
  x = fminf(15.f, fmaxf(-15.f, x));
  float e = __expf(-2.f * x);
  return (1.f - e) / (1.f + e);
}

// grid barrier: release (vmcnt drain + L2 writeback) -> spin at MALL -> acquire (L1/L2 inv)
__device__ __forceinline__ void gbar(unsigned* bar, unsigned target) {
  __syncthreads();
  if (threadIdx.x == 0) {
    __hip_atomic_fetch_add(bar, 1u, __ATOMIC_RELEASE, __HIP_MEMORY_SCOPE_AGENT);
    while (__hip_atomic_load(bar, __ATOMIC_RELAXED, __HIP_MEMORY_SCOPE_AGENT) < target)
      __builtin_amdgcn_s_sleep(2);
    __threadfence();
  }
  __syncthreads();
}

__global__ void __launch_bounds__(NTHR, 1)
lstm_all(const float* __restrict__ x,
         const float* __restrict__ encW, const float* __restrict__ encU, const float* __restrict__ encB,
         const float* __restrict__ celW, const float* __restrict__ celU, const float* __restrict__ celB,
         const float* __restrict__ denW, const float* __restrict__ denB,
         float* __restrict__ out,
         short* __restrict__ hbf, unsigned* __restrict__ bar)
{
  extern __shared__ char smem[];                  // [B_lds 147456 | zscr 16384]
  float* zs = (float*)(smem + BLDS_BYTES);

  const int tid  = threadIdx.x;
  const int wg   = blockIdx.x;
  const int gtid = wg * NTHR + tid;
  unsigned syncno = 0;

  const int wgc = wg & 63, wgr = wg >> 6;         // colgroup, rowgroup

  // ---- init: zero h buf0 + out ----
  if (gtid < 32768) { short8 z = (short8)0; *(short8*)(hbf + (size_t)gtid * 8) = z; }
  if (gtid < 1536)  { float4v z = {0.f,0.f,0.f,0.f}; *(float4v*)(out + gtid * 4) = z; }

  // ---- load encoder weight slice into LDS (bf16, XOR-swizzled rows) ----
  // B_lds row r = gate*16 + c  -> global n = gate*1024 + wgc*16 + c ; k = 0..1151
  {
    const int r = tid & 63, slot = tid >> 6;
    const int n = (r >> 4) * 1024 + wgc * 16 + (r & 15);
    for (int i = 0; i < 5; ++i) {
      int kk = slot + 8 * i;
      if (kk < 36) {
        for (int j8 = 0; j8 < 4; ++j8) {
          short8 v;
#pragma unroll
          for (int j = 0; j < 8; ++j) {
            int k = kk * 32 + j8 * 8 + j;
            float f = (k < 128) ? encW[(size_t)k * 4096 + n]
                                : encU[(size_t)(k - 128) * 4096 + n];
            v[j] = bf16r(f);
          }
          uint32_t byte = ((uint32_t)(r * 1152 + kk * 32 + j8 * 8) * 2u) ^ (uint32_t)((r & 7) << 4);
          *(short8*)(smem + byte) = v;
        }
      }
    }
  }
  gbar(bar, ++syncno * NWG);

  // ---- identities ----
  const int lane = tid & 63, wv = tid >> 6;
  const int l15 = lane & 15, lq = lane >> 4;
  const int mq = wv & 1, ks = wv >> 1;            // wave -> (m-half, K-slice)
  const int arow0 = wgr * 64 + mq * 32 + l15;     // A rows for frag mf=0 / mf=1
  const int arow1 = arow0 + 16;

  // B-frag addressing: rB = nf*16 + l15
  uint32_t bbase[4], bmask[4];
#pragma unroll
  for (int nf = 0; nf < 4; ++nf) {
    int rB = nf * 16 + l15;
    bbase[nf] = (uint32_t)((rB * 1152 + lq * 8) * 2);
    bmask[nf] = (uint32_t)((rB & 7) << 4);
  }

  // epilogue ids
  const int col16 = tid & 15, rp = tid >> 4;      // 32 row-pairs x 16 cols
  const int gcol  = wgc * 16 + col16;
  const int grow0 = wgr * 64 + 2 * rp, grow1 = grow0 + 1;
  const float bei = encB[gcol], bef = encB[1024 + gcol], beg = encB[2048 + gcol], beo = encB[3072 + gcol];
  const float bci = celB[gcol], bcf = celB[1024 + gcol], bcg = celB[2048 + gcol], bco = celB[3072 + gcol];
  const float dw = denW[gcol];
  const float db = denB[0];
  float c0 = 0.f, c1 = 0.f;
  int cur = 0;

  // ================= encoder: 512 steps =================
  for (int t = 0; t < 512; ++t) {
    { // zero z-scratch
      int zr = tid >> 3, zc = (tid & 7) * 8;
      float4v z = {0.f,0.f,0.f,0.f};
      *(float4v*)(zs + zr * 64 + zc)     = z;
      *(float4v*)(zs + zr * 64 + zc + 4) = z;
    }
    __syncthreads();

    float4v acc[2][4];
#pragma unroll
    for (int a = 0; a < 2; ++a)
#pragma unroll
      for (int b = 0; b < 4; ++b) acc[a][b] = (float4v){0.f,0.f,0.f,0.f};

    const short* hb = hbf + (size_t)cur * HBF_SHORTS;

#pragma unroll
    for (int kk = 0; kk < 9; ++kk) {
      const int Kg = ks * 288 + kk * 32;
      short8 a0, a1;
      if (ks == 0 && kk < 4) {                     // x part (K 0..127), f32 -> bf16
        const float* xp0 = x + ((size_t)arow0 * 512 + t) * 128 + Kg + lq * 8;
        const float* xp1 = x + ((size_t)arow1 * 512 + t) * 128 + Kg + lq * 8;
        float4v u0 = *(const float4v*)xp0, u1 = *(const float4v*)(xp0 + 4);
        float4v w0 = *(const float4v*)xp1, w1 = *(const float4v*)(xp1 + 4);
#pragma unroll
        for (int j = 0; j < 4; ++j) { a0[j] = bf16r(u0[j]); a0[4+j] = bf16r(u1[j]); }
#pragma unroll
        for (int j = 0; j < 4; ++j) { a1[j] = bf16r(w0[j]); a1[4+j] = bf16r(w1[j]); }
      } else {                                     // h part (K 128..1151)
        a0 = *(const short8*)(hb + (size_t)arow0 * 1024 + (Kg - 128) + lq * 8);
        a1 = *(const short8*)(hb + (size_t)arow1 * 1024 + (Kg - 128) + lq * 8);
      }
#pragma unroll
      for (int nf = 0; nf < 4; ++nf) {
        const short8 b = *(const short8*)(smem + ((bbase[nf] + 2u * (uint32_t)Kg) ^ bmask[nf]));
        acc[0][nf] = __builtin_amdgcn_mfma_f32_16x16x32_bf16(a0, b, acc[0][nf], 0, 0, 0);
        acc[1][nf] = __builtin_amdgcn_mfma_f32_16x16x32_bf16(a1, b, acc[1][nf], 0, 0, 0);
      }
    }

    // partial-z reduction into LDS
#pragma unroll
    for (int mf = 0; mf < 2; ++mf)
#pragma unroll
      for (int nf = 0; nf < 4; ++nf)
#pragma unroll
        for (int e = 0; e < 4; ++e) {
          int row = mq * 32 + mf * 16 + lq * 4 + e;
          int col = (nf * 16 + l15) ^ (((row >> 2) & 1) << 4);
          atomicAdd(&zs[row * 64 + col], acc[mf][nf][e]);
        }
    __syncthreads();

    { // gate epilogue: 2 rows per thread
      const int r0 = 2 * rp, r1 = r0 + 1;
      const int sw = ((r0 >> 2) & 1) << 4;         // same for r0 and r1 (r0 even)
      float zi0 = zs[r0*64 + (( 0+col16)^sw)] + bei;
      float zf0 = zs[r0*64 + ((16+col16)^sw)] + bef;
      float zg0 = zs[r0*64 + ((32+col16)^sw)] + beg;
      float zo0 = zs[r0*64 + ((48+col16)^sw)] + beo;
      float zi1 = zs[r1*64 + (( 0+col16)^sw)] + bei;
      float zf1 = zs[r1*64 + ((16+col16)^sw)] + bef;
      float zg1 = zs[r1*64 + ((32+col16)^sw)] + beg;
      float zo1 = zs[r1*64 + ((48+col16)^sw)] + beo;
      c0 = sig_(zf0) * c0 + sig_(zi0) * tanh_(zg0);
      c1 = sig_(zf1) * c1 + sig_(zi1) * tanh_(zg1);
      float h0 = sig_(zo0) * tanh_(c0);
      float h1 = sig_(zo1) * tanh_(c1);
      short* hn = hbf + (size_t)(cur ^ 1) * HBF_SHORTS;
      hn[(size_t)grow0 * 1024 + gcol] = bf16r(h0);
      hn[(size_t)grow1 * 1024 + gcol] = bf16r(h1);
    }
    cur ^= 1;
    gbar(bar, ++syncno * NWG);
  }

  // ---- reload LDS with decoder weights St = (cell_W + cell_U)^T, k 0..1023 ----
  {
    const int r = tid & 63, slot = tid >> 6;
    const int n = (r >> 4) * 1024 + wgc * 16 + (r & 15);
    for (int i = 0; i < 4; ++i) {
      int kk = slot + 8 * i;                       // 0..31
      for (int j8 = 0; j8 < 4; ++j8) {
        short8 v;
#pragma unroll
        for (int j = 0; j < 8; ++j) {
          int k = kk * 32 + j8 * 8 + j;
          float f = celW[(size_t)k * 4096 + n] + celU[(size_t)k * 4096 + n];
          v[j] = bf16r(f);
        }
        uint32_t byte = ((uint32_t)(r * 1152 + kk * 32 + j8 * 8) * 2u) ^ (uint32_t)((r & 7) << 4);
        *(short8*)(smem + byte) = v;
      }
    }
  }
  __syncthreads();

  // ================= decoder: 24 steps (x_in == h => z = h @ (W+U)) =================
  for (int td = 0; td < 24; ++td) {
    {
      int zr = tid >> 3, zc = (tid & 7) * 8;
      float4v z = {0.f,0.f,0.f,0.f};
      *(float4v*)(zs + zr * 64 + zc)     = z;
      *(float4v*)(zs + zr * 64 + zc + 4) = z;
    }
    __syncthreads();

    float4v acc[2][4];
#pragma unroll
    for (int a = 0; a < 2; ++a)
#pragma unroll
      for (int b = 0; b < 4; ++b) acc[a][b] = (float4v){0.f,0.f,0.f,0.f};

    const short* hb = hbf + (size_t)cur * HBF_SHORTS;

#pragma unroll
    for (int kk = 0; kk < 8; ++kk) {
      const int Kg = ks * 256 + kk * 32;
      short8 a0 = *(const short8*)(hb + (size_t)arow0 * 1024 + Kg + lq * 8);
      short8 a1 = *(const short8*)(hb + (size_t)arow1 * 1024 + Kg + lq * 8);
#pragma unroll
      for (int nf = 0; nf < 4; ++nf) {
        const short8 b = *(const short8*)(smem + ((bbase[nf] + 2u * (uint32_t)Kg) ^ bmask[nf]));
        acc[0][nf] = __builtin_amdgcn_mfma_f32_16x16x32_bf16(a0, b, acc[0][nf], 0, 0, 0);
        acc[1][nf] = __builtin_amdgcn_mfma_f32_16x16x32_bf16(a1, b, acc[1][nf], 0, 0, 0);
      }
    }

#pragma unroll
    for (int mf = 0; mf < 2; ++mf)
#pragma unroll
      for (int nf = 0; nf < 4; ++nf)
#pragma unroll
        for (int e = 0; e < 4; ++e) {
          int row = mq * 32 + mf * 16 + lq * 4 + e;
          int col = (nf * 16 + l15) ^ (((row >> 2) & 1) << 4);
          atomicAdd(&zs[row * 64 + col], acc[mf][nf][e]);
        }
    __syncthreads();

    {
      const int r0 = 2 * rp, r1 = r0 + 1;
      const int sw = ((r0 >> 2) & 1) << 4;
      float zi0 = zs[r0*64 + (( 0+col16)^sw)] + bci;
      float zf0 = zs[r0*64 + ((16+col16)^sw)] + bcf;
      float zg0 = zs[r0*64 + ((32+col16)^sw)] + bcg;
      float zo0 = zs[r0*64 + ((48+col16)^sw)] + bco;
      float zi1 = zs[r1*64 + (( 0+col16)^sw)] + bci;
      float zf1 = zs[r1*64 + ((16+col16)^sw)] + bcf;
      float zg1 = zs[r1*64 + ((32+col16)^sw)] + bcg;
      float zo1 = zs[r1*64 + ((48+col16)^sw)] + bco;
      c0 = sig_(zf0) * c0 + sig_(zi0) * tanh_(zg0);
      c1 = sig_(zf1) * c1 + sig_(zi1) * tanh_(zg1);
      float h0 = sig_(zo0) * tanh_(c0);
      float h1 = sig_(zo1) * tanh_(c1);

      // dense head: pred = h @ dense_W + b  (reduce 16 cols -> 64 partials/row)
      float p0 = h0 * dw, p1 = h1 * dw;
#pragma unroll
      for (int m = 1; m < 16; m <<= 1) {
        p0 += __shfl_xor(p0, m);
        p1 += __shfl_xor(p1, m);
      }
      short* hn = hbf + (size_t)(cur ^ 1) * HBF_SHORTS;
      hn[(size_t)grow0 * 1024 + gcol] = bf16r(h0);
      hn[(size_t)grow1 * 1024 + gcol] = bf16r(h1);
      if (col16 == 0) {
        atomicAdd(&out[grow0 * 24 + td], p0 + (wgc == 0 ? db : 0.f));
        atomicAdd(&out[grow1 * 24 + td], p1 + (wgc == 0 ? db : 0.f));
      }
    }
    cur ^= 1;
    gbar(bar, ++syncno * NWG);
  }
}

extern "C" void kernel_launch(void* const* d_in, const int* in_sizes, int n_in,
                              void* d_out, int out_size, void* d_ws, size_t ws_size,
                              hipStream_t stream) {
  const float* x    = (const float*)d_in[0];
  const float* encW = (const float*)d_in[1];
  const float* encU = (const float*)d_in[2];
  const float* encB = (const float*)d_in[3];
  const float* celW = (const float*)d_in[4];
  const float* celU = (const float*)d_in[5];
  const float* celB = (const float*)d_in[6];
  const float* denW = (const float*)d_in[7];
  const float* denB = (const float*)d_in[8];
  float* out = (float*)d_out;

  if (ws_size < WS_NEED) return;                  // visible failure, no OOB

  short*    hbf = (short*)d_ws;
  unsigned* bar = (unsigned*)((char*)d_ws + 2ull * HBF_SHORTS * 2ull);

  hipMemsetAsync(bar, 0, 256, stream);
  hipFuncSetAttribute((const void*)lstm_all,
                      hipFuncAttributeMaxDynamicSharedMemorySize, SMEM_BYTES);

  void* args[] = { (void*)&x, (void*)&encW, (void*)&encU, (void*)&encB,
                   (void*)&celW, (void*)&celU, (void*)&celB,
                   (void*)&denW, (void*)&denB,
                   (void*)&out, (void*)&hbf, (void*)&bar };
  hipLaunchCooperativeKernel((void*)lstm_all, dim3(NWG), dim3(NTHR), args,
                             (unsigned)SMEM_BYTES, stream);
}

// Round 5
// 13987.106 us; speedup vs baseline: 1.6602x; 1.6602x over previous
//
#include <hip/hip_runtime.h>
#include <cstdint>

#define NWG  256
#define NTHR 512
#define HBUF_U64 65536ull                 // one h buffer: 256*1024 bf16 = 64K u64
#define WS_NEED  (HBUF_U64 * 2ull * 8ull + 512ull)
#define BLDS_BYTES 147456                 // 64 rows * 1152 K * 2B (XOR-swizzled)
#define SMEM_BYTES (BLDS_BYTES + 16384)   // + zs 64*64 f32 = 160 KiB

typedef __attribute__((ext_vector_type(8))) short  short8;
typedef __attribute__((ext_vector_type(4))) float  float4v;
typedef unsigned long long u64;

#define ALD(p)    __hip_atomic_load((p), __ATOMIC_RELAXED, __HIP_MEMORY_SCOPE_AGENT)
#define AST(p, v) __hip_atomic_store((p), (v), __ATOMIC_RELAXED, __HIP_MEMORY_SCOPE_AGENT)

__device__ __forceinline__ short bf16r(float f) {
  union { float f; uint32_t u; } v; v.f = f;
  uint32_t r = (v.u + 0x7FFFu + ((v.u >> 16) & 1u)) >> 16;   // RNE
  return (short)(uint16_t)r;
}
__device__ __forceinline__ float sig_(float x)  { return 1.f / (1.f + __expf(-x)); }
__device__ __forceinline__ float tanh_(float x) {
  x = fminf(15.f, fmaxf(-15.f, x));
  float e = __expf(-2.f * x);
  return (1.f - e) / (1.f + e);
}

__global__ void __launch_bounds__(NTHR, 1)
lstm_all(const float* __restrict__ x,
         const float* __restrict__ encW, const float* __restrict__ encU, const float* __restrict__ encB,
         const float* __restrict__ celW, const float* __restrict__ celU, const float* __restrict__ celB,
         const float* __restrict__ denW, const float* __restrict__ denB,
         float* __restrict__ out,
         u64* __restrict__ hb, unsigned* __restrict__ barp)
{
  extern __shared__ char smem[];                  // [B_lds 147456 | zs 16384]
  float* zs = (float*)(smem + BLDS_BYTES);

  const int tid = threadIdx.x, wg = blockIdx.x;
  const int wgc = wg & 63, wgr = wg >> 6;         // colgroup, rowgroup
  unsigned* bar = barp + wgr * 32;                // per-rowgroup barrier line
  unsigned syncno = 0;

  // ---- init: zero own h0 slab (MALL-direct) + out (rowgroup's slice) ----
  if (tid < 256)
    AST(hb + (size_t)wgc * 1024 + (size_t)wgr * 256 + tid, 0ull);
  if (wgc == 0)
    for (int i = tid; i < 768; i += NTHR)         // 64 rows * 24 f32 = 768 u64
      AST((u64*)out + (size_t)wgr * 768 + i, 0ull);

  // ---- encoder weight slice -> LDS (bf16, XOR-swizzled rows) ----
  {
    const int r = tid & 63, slot = tid >> 6;
    const int n = (r >> 4) * 1024 + wgc * 16 + (r & 15);
    for (int i = 0; i < 5; ++i) {
      int kk = slot + 8 * i;
      if (kk < 36) {
        for (int j8 = 0; j8 < 4; ++j8) {
          short8 v;
#pragma unroll
          for (int j = 0; j < 8; ++j) {
            int k = kk * 32 + j8 * 8 + j;
            float f = (k < 128) ? encW[(size_t)k * 4096 + n]
                                : encU[(size_t)(k - 128) * 4096 + n];
            v[j] = bf16r(f);
          }
          uint32_t byte = ((uint32_t)(r * 1152 + kk * 32 + j8 * 8) * 2u) ^ (uint32_t)((r & 7) << 4);
          *(short8*)(smem + byte) = v;
        }
      }
    }
  }

  // ---- ids ----
  const int lane = tid & 63, wv = tid >> 6;
  const int l15 = lane & 15, lq = lane >> 4;
  const int mq = wv & 1, ks = wv >> 1;            // wave -> (m-half, K-slice)
  uint32_t bbase[4], bmask[4];
#pragma unroll
  for (int nf = 0; nf < 4; ++nf) {
    int rB = nf * 16 + l15;
    bbase[nf] = (uint32_t)((rB * 1152 + lq * 8) * 2);
    bmask[nf] = (uint32_t)((rB & 7) << 4);
  }
  const int erow = tid >> 3, ecp = tid & 7;       // epilogue: row (local), col-pair
  const int gcol0 = wgc * 16 + 2 * ecp, gcol1 = gcol0 + 1;
  const int growg = wgr * 64 + erow;              // global row
  const int erot  = ((erow >> 2) & 3) << 4;       // zs col swizzle (matches lq<<4)
  const float bei0 = encB[gcol0], bei1 = encB[gcol1];
  const float bef0 = encB[1024 + gcol0], bef1 = encB[1024 + gcol1];
  const float beg0 = encB[2048 + gcol0], beg1 = encB[2048 + gcol1];
  const float beo0 = encB[3072 + gcol0], beo1 = encB[3072 + gcol1];
  const float bci0 = celB[gcol0], bci1 = celB[gcol1];
  const float bcf0 = celB[1024 + gcol0], bcf1 = celB[1024 + gcol1];
  const float bcg0 = celB[2048 + gcol0], bcg1 = celB[2048 + gcol1];
  const float bco0 = celB[3072 + gcol0], bco1 = celB[3072 + gcol1];
  const float dw0 = denW[gcol0], dw1 = denW[gcol1], db = denB[0];
  float cA = 0.f, cB = 0.f;
  int cur = 0;
  float4v acc[2][4];

  auto xpart = [&](int t) {                       // x_t @ W : wave ks does K-tile ks*32
    const int Kg = ks * 32;
    const float* xp0 = x + ((size_t)(wgr * 64 + mq * 32 + l15) * 512 + (size_t)t) * 128 + Kg + lq * 8;
    const float* xp1 = xp0 + (size_t)16 * 512 * 128;
    float4v u0 = *(const float4v*)xp0, u1 = *(const float4v*)(xp0 + 4);
    float4v w0 = *(const float4v*)xp1, w1 = *(const float4v*)(xp1 + 4);
    short8 a0, a1;
#pragma unroll
    for (int j = 0; j < 4; ++j) {
      a0[j] = bf16r(u0[j]); a0[4 + j] = bf16r(u1[j]);
      a1[j] = bf16r(w0[j]); a1[4 + j] = bf16r(w1[j]);
    }
#pragma unroll
    for (int nf = 0; nf < 4; ++nf) {
      short8 b = *(const short8*)(smem + ((bbase[nf] + 2u * (uint32_t)Kg) ^ bmask[nf]));
      acc[0][nf] = __builtin_amdgcn_mfma_f32_16x16x32_bf16(a0, b, acc[0][nf], 0, 0, 0);
      acc[1][nf] = __builtin_amdgcn_mfma_f32_16x16x32_bf16(a1, b, acc[1][nf], 0, 0, 0);
    }
  };

  auto hpart = [&](const u64* hbase, int wk0) {   // h @ U-slice, MALL-direct A loads
    const int rbase = wgr * 64 + mq * 32 + l15;
#pragma unroll
    for (int kk = 0; kk < 8; ++kk) {
      const int kc = ks * 256 + kk * 32;
      const int c0 = kc + lq * 8;
      const size_t bidx = (size_t)(c0 >> 4) * 1024 + (size_t)rbase * 4 + (size_t)((c0 & 15) >> 2);
      union { u64 q[2]; short8 s; } ua, ub;
      ua.q[0] = ALD(hbase + bidx);      ua.q[1] = ALD(hbase + bidx + 1);
      ub.q[0] = ALD(hbase + bidx + 64); ub.q[1] = ALD(hbase + bidx + 65);   // +16 rows
      const uint32_t Kw = (uint32_t)(wk0 + kc);
#pragma unroll
      for (int nf = 0; nf < 4; ++nf) {
        short8 b = *(const short8*)(smem + ((bbase[nf] + 2u * Kw) ^ bmask[nf]));
        acc[0][nf] = __builtin_amdgcn_mfma_f32_16x16x32_bf16(ua.s, b, acc[0][nf], 0, 0, 0);
        acc[1][nf] = __builtin_amdgcn_mfma_f32_16x16x32_bf16(ub.s, b, acc[1][nf], 0, 0, 0);
      }
    }
  };

  auto reduce_zs = [&]() {                        // 2-way-max bank pattern (free)
#pragma unroll
    for (int mf = 0; mf < 2; ++mf)
#pragma unroll
      for (int nf = 0; nf < 4; ++nf)
#pragma unroll
        for (int e = 0; e < 4; ++e) {
          int row = mq * 32 + mf * 16 + lq * 4 + e;
          int col = (nf * 16 + l15) ^ (lq << 4);
          atomicAdd(&zs[row * 64 + col], acc[mf][nf][e]);
        }
  };

  auto st_reload = [&]() {                        // decoder weights (cell_W+cell_U)^T -> LDS
    const int r = tid & 63, slot = tid >> 6;
    const int n = (r >> 4) * 1024 + wgc * 16 + (r & 15);
    for (int i = 0; i < 4; ++i) {
      int kk = slot + 8 * i;                      // 0..31
      for (int j8 = 0; j8 < 4; ++j8) {
        short8 v;
#pragma unroll
        for (int j = 0; j < 8; ++j) {
          int k = kk * 32 + j8 * 8 + j;
          float f = celW[(size_t)k * 4096 + n] + celU[(size_t)k * 4096 + n];
          v[j] = bf16r(f);
        }
        uint32_t byte = ((uint32_t)(r * 1152 + kk * 32 + j8 * 8) * 2u) ^ (uint32_t)((r & 7) << 4);
        *(short8*)(smem + byte) = v;
      }
    }
  };

  // barrier with overlapped zs-zero + next-step x-part (+ optional weight reload)
  auto barrier_overlap = [&](int xt, bool reload) {
    asm volatile("s_waitcnt vmcnt(0)" ::: "memory");   // h stores at MALL
    __syncthreads();
    if (tid == 0)
      __hip_atomic_fetch_add(bar, 1u, __ATOMIC_RELAXED, __HIP_MEMORY_SCOPE_AGENT);
    ++syncno;
    { float* p = zs + tid * 8; float4v zz = {0.f,0.f,0.f,0.f};
      *(float4v*)p = zz; *(float4v*)(p + 4) = zz; }        // linear, conflict-free
#pragma unroll
    for (int mf = 0; mf < 2; ++mf)
#pragma unroll
      for (int nf = 0; nf < 4; ++nf) acc[mf][nf] = (float4v){0.f,0.f,0.f,0.f};
    if (xt >= 0) xpart(xt);
    if (reload) st_reload();
    if (tid == 0) {
      const unsigned tgt = syncno * 64u;
      while (ALD(bar) < tgt) __builtin_amdgcn_s_sleep(1);
    }
    __syncthreads();
  };

  auto epilogue = [&](bool dec, int td) {
    const float* zr = zs + erow * 64;
    float2 I = *(const float2*)(zr + (( 0 + 2 * ecp) ^ erot));
    float2 F = *(const float2*)(zr + ((16 + 2 * ecp) ^ erot));
    float2 G = *(const float2*)(zr + ((32 + 2 * ecp) ^ erot));
    float2 O = *(const float2*)(zr + ((48 + 2 * ecp) ^ erot));
    float i0, i1, f0, f1, g0, g1, o0, o1;
    if (!dec) { i0=I.x+bei0; i1=I.y+bei1; f0=F.x+bef0; f1=F.y+bef1;
                g0=G.x+beg0; g1=G.y+beg1; o0=O.x+beo0; o1=O.y+beo1; }
    else      { i0=I.x+bci0; i1=I.y+bci1; f0=F.x+bcf0; f1=F.y+bcf1;
                g0=G.x+bcg0; g1=G.y+bcg1; o0=O.x+bco0; o1=O.y+bco1; }
    cA = sig_(f0) * cA + sig_(i0) * tanh_(g0);
    cB = sig_(f1) * cB + sig_(i1) * tanh_(g1);
    float hA = sig_(o0) * tanh_(cA);
    float hB = sig_(o1) * tanh_(cB);
    unsigned hp = (unsigned)(unsigned short)bf16r(hA)
                | ((unsigned)(unsigned short)bf16r(hB) << 16);
    unsigned* h32 = (unsigned*)hb;
    size_t idx = (size_t)(cur ^ 1) * 131072 + (size_t)wgc * 2048 + (size_t)growg * 8 + ecp;
    AST(h32 + idx, hp);                            // MALL-direct, coalesced
    if (dec) {
      float p = hA * dw0 + hB * dw1;
      p += __shfl_xor(p, 1); p += __shfl_xor(p, 2); p += __shfl_xor(p, 4);
      if (ecp == 0)
        atomicAdd(&out[(size_t)growg * 24 + td], p + (wgc == 0 ? db : 0.f));
    }
  };

  // ================= run =================
  barrier_overlap(0, false);                       // init barrier; overlap xpart(t=0)
  for (int t = 0; t < 512; ++t) {
    hpart(hb + (size_t)cur * HBUF_U64, 128);
    reduce_zs();
    __syncthreads();
    epilogue(false, 0);
    cur ^= 1;
    if (t < 511) barrier_overlap(t + 1, false);
    else         barrier_overlap(-1, true);        // overlap decoder weight reload
  }
  for (int td = 0; td < 24; ++td) {
    hpart(hb + (size_t)cur * HBUF_U64, 0);
    reduce_zs();
    __syncthreads();
    epilogue(true, td);
    cur ^= 1;
    if (td < 23) barrier_overlap(-1, false);
  }
}

extern "C" void kernel_launch(void* const* d_in, const int* in_sizes, int n_in,
                              void* d_out, int out_size, void* d_ws, size_t ws_size,
                              hipStream_t stream) {
  const float* x    = (const float*)d_in[0];
  const float* encW = (const float*)d_in[1];
  const float* encU = (const float*)d_in[2];
  const float* encB = (const float*)d_in[3];
  const float* celW = (const float*)d_in[4];
  const float* celU = (const float*)d_in[5];
  const float* celB = (const float*)d_in[6];
  const float* denW = (const float*)d_in[7];
  const float* denB = (const float*)d_in[8];
  float* out = (float*)d_out;

  if (ws_size < WS_NEED) return;                   // visible failure, no OOB

  u64*      hb  = (u64*)d_ws;
  unsigned* bar = (unsigned*)((char*)d_ws + HBUF_U64 * 2ull * 8ull);

  hipMemsetAsync(bar, 0, 512, stream);
  hipFuncSetAttribute((const void*)lstm_all,
                      hipFuncAttributeMaxDynamicSharedMemorySize, SMEM_BYTES);

  void* args[] = { (void*)&x, (void*)&encW, (void*)&encU, (void*)&encB,
                   (void*)&celW, (void*)&celU, (void*)&celB,
                   (void*)&denW, (void*)&denB,
                   (void*)&out, (void*)&hb, (void*)&bar };
  hipLaunchCooperativeKernel((void*)lstm_all, dim3(NWG), dim3(NTHR), args,
                             (unsigned)SMEM_BYTES, stream);
}

// Round 6
// 13962.950 us; speedup vs baseline: 1.6631x; 1.0017x over previous
//
#include <hip/hip_runtime.h>
#include <cstdint>

#define NWG  256
#define NTHR 512
#define HBUF_U64 65536ull                 // one h buffer: 256*1024 bf16 = 64K u64
#define WS_NEED  (HBUF_U64 * 2ull * 8ull + 512ull)
#define BLDS_BYTES 147456                 // 64 rows * 1152 K * 2B (XOR-swizzled)
#define SMEM_BYTES (BLDS_BYTES + 16384)   // + zs 64*64 f32 = 160 KiB

typedef __attribute__((ext_vector_type(8))) short  short8;
typedef __attribute__((ext_vector_type(4))) float  float4v;
typedef unsigned long long u64;

#define ALD(p)    __hip_atomic_load((p), __ATOMIC_RELAXED, __HIP_MEMORY_SCOPE_AGENT)
#define AST(p, v) __hip_atomic_store((p), (v), __ATOMIC_RELAXED, __HIP_MEMORY_SCOPE_AGENT)

__device__ __forceinline__ short bf16r(float f) {
  union { float f; uint32_t u; } v; v.f = f;
  uint32_t r = (v.u + 0x7FFFu + ((v.u >> 16) & 1u)) >> 16;   // RNE
  return (short)(uint16_t)r;
}
__device__ __forceinline__ float sig_(float x)  { return 1.f / (1.f + __expf(-x)); }
__device__ __forceinline__ float tanh_(float x) {
  x = fminf(15.f, fmaxf(-15.f, x));
  float e = __expf(-2.f * x);
  return (1.f - e) / (1.f + e);
}

// poll a u32 straight from MALL (bypass L1/L2) — no stale-line detection latency
__device__ __forceinline__ unsigned mall_poll(const unsigned* p) {
  unsigned v;
  unsigned long long a = (unsigned long long)p;
  asm volatile("global_load_dword %0, %1, off sc0 sc1\n\t"
               "s_waitcnt vmcnt(0)"
               : "=v"(v) : "v"(a) : "memory");
  return v;
}

__global__ void __launch_bounds__(NTHR, 1)
lstm_all(const float* __restrict__ x,
         const float* __restrict__ encW, const float* __restrict__ encU, const float* __restrict__ encB,
         const float* __restrict__ celW, const float* __restrict__ celU, const float* __restrict__ celB,
         const float* __restrict__ denW, const float* __restrict__ denB,
         float* __restrict__ out,
         u64* __restrict__ hb, unsigned* __restrict__ barp)
{
  extern __shared__ char smem[];                  // [B_lds 147456 | zs 16384]
  float* zs = (float*)(smem + BLDS_BYTES);

  const int tid = threadIdx.x, wg = blockIdx.x;
  // rowgroup -> XCD-pair locality: XCD = wg%8; rowgroup fixed by wg&7, col by upper bits
  const int wgr = (wg & 7) >> 1;                  // rowgroup on XCDs {2r, 2r+1}
  const int wgc = ((wg >> 3) << 1) | (wg & 1);    // colgroup 0..63 (bijective)
  unsigned* bar = barp + wgr * 32;                // per-rowgroup barrier line
  unsigned syncno = 0;

  // ---- init: zero own h0 slab + out (rowgroup's slice) ----
  if (tid < 256)
    AST(hb + (size_t)wgc * 1024 + (size_t)wgr * 256 + tid, 0ull);
  if (wgc == 0)
    for (int i = tid; i < 768; i += NTHR)         // 64 rows * 24 f32 = 768 u64
      AST((u64*)out + (size_t)wgr * 768 + i, 0ull);

  // ---- encoder weight slice -> LDS (bf16, XOR-swizzled rows) ----
  {
    const int r = tid & 63, slot = tid >> 6;
    const int n = (r >> 4) * 1024 + wgc * 16 + (r & 15);
    for (int i = 0; i < 5; ++i) {
      int kk = slot + 8 * i;
      if (kk < 36) {
        for (int j8 = 0; j8 < 4; ++j8) {
          short8 v;
#pragma unroll
          for (int j = 0; j < 8; ++j) {
            int k = kk * 32 + j8 * 8 + j;
            float f = (k < 128) ? encW[(size_t)k * 4096 + n]
                                : encU[(size_t)(k - 128) * 4096 + n];
            v[j] = bf16r(f);
          }
          uint32_t byte = ((uint32_t)(r * 1152 + kk * 32 + j8 * 8) * 2u) ^ (uint32_t)((r & 7) << 4);
          *(short8*)(smem + byte) = v;
        }
      }
    }
  }

  // ---- ids ----
  const int lane = tid & 63, wv = tid >> 6;
  const int l15 = lane & 15, lq = lane >> 4;
  const int mq = wv & 1, ks = wv >> 1;            // wave -> (m-half, K-slice)
  uint32_t bbase[4], bmask[4];
#pragma unroll
  for (int nf = 0; nf < 4; ++nf) {
    int rB = nf * 16 + l15;
    bbase[nf] = (uint32_t)((rB * 1152 + lq * 8) * 2);
    bmask[nf] = (uint32_t)((rB & 7) << 4);
  }
  const int erow = tid >> 3, ecp = tid & 7;       // epilogue: row (local), col-pair
  const int gcol0 = wgc * 16 + 2 * ecp, gcol1 = gcol0 + 1;
  const int growg = wgr * 64 + erow;              // global row
  const int erot  = ((erow >> 2) & 3) << 4;       // zs col swizzle (matches lq<<4)
  const float bei0 = encB[gcol0], bei1 = encB[gcol1];
  const float bef0 = encB[1024 + gcol0], bef1 = encB[1024 + gcol1];
  const float beg0 = encB[2048 + gcol0], beg1 = encB[2048 + gcol1];
  const float beo0 = encB[3072 + gcol0], beo1 = encB[3072 + gcol1];
  const float bci0 = celB[gcol0], bci1 = celB[gcol1];
  const float bcf0 = celB[1024 + gcol0], bcf1 = celB[1024 + gcol1];
  const float bcg0 = celB[2048 + gcol0], bcg1 = celB[2048 + gcol1];
  const float bco0 = celB[3072 + gcol0], bco1 = celB[3072 + gcol1];
  const float dw0 = denW[gcol0], dw1 = denW[gcol1], db = denB[0];
  float cA = 0.f, cB = 0.f;
  int cur = 0;
  float4v acc[2][4];

  auto xpart = [&](int t) {                       // x_t @ W : wave ks does K-tile ks*32
    const int Kg = ks * 32;
    const float* xp0 = x + ((size_t)(wgr * 64 + mq * 32 + l15) * 512 + (size_t)t) * 128 + Kg + lq * 8;
    const float* xp1 = xp0 + (size_t)16 * 512 * 128;
    float4v u0 = *(const float4v*)xp0, u1 = *(const float4v*)(xp0 + 4);
    float4v w0 = *(const float4v*)xp1, w1 = *(const float4v*)(xp1 + 4);
    short8 a0, a1;
#pragma unroll
    for (int j = 0; j < 4; ++j) {
      a0[j] = bf16r(u0[j]); a0[4 + j] = bf16r(u1[j]);
      a1[j] = bf16r(w0[j]); a1[4 + j] = bf16r(w1[j]);
    }
#pragma unroll
    for (int nf = 0; nf < 4; ++nf) {
      short8 b = *(const short8*)(smem + ((bbase[nf] + 2u * (uint32_t)Kg) ^ bmask[nf]));
      acc[0][nf] = __builtin_amdgcn_mfma_f32_16x16x32_bf16(a0, b, acc[0][nf], 0, 0, 0);
      acc[1][nf] = __builtin_amdgcn_mfma_f32_16x16x32_bf16(a1, b, acc[1][nf], 0, 0, 0);
    }
  };

  // h @ U-slice: hoist ALL 32 loads (static-indexed -> registers) before MFMAs
  auto hpart = [&](const u64* hbase, int wk0) {
    const int rbase = wgr * 64 + mq * 32 + l15;
    u64 q0[8], q1[8], q2[8], q3[8];
#pragma unroll
    for (int kk = 0; kk < 8; ++kk) {
      const int kc = ks * 256 + kk * 32;
      const int c0 = kc + lq * 8;
      const size_t bidx = (size_t)(c0 >> 4) * 1024 + (size_t)rbase * 4 + (size_t)((c0 & 15) >> 2);
      q0[kk] = ALD(hbase + bidx);
      q1[kk] = ALD(hbase + bidx + 1);
      q2[kk] = ALD(hbase + bidx + 64);      // +16 rows
      q3[kk] = ALD(hbase + bidx + 65);
    }
#pragma unroll
    for (int kk = 0; kk < 8; ++kk) {
      const int kc = ks * 256 + kk * 32;
      union { u64 q[2]; short8 s; } ua, ub;
      ua.q[0] = q0[kk]; ua.q[1] = q1[kk];
      ub.q[0] = q2[kk]; ub.q[1] = q3[kk];
      const uint32_t Kw = (uint32_t)(wk0 + kc);
#pragma unroll
      for (int nf = 0; nf < 4; ++nf) {
        short8 b = *(const short8*)(smem + ((bbase[nf] + 2u * Kw) ^ bmask[nf]));
        acc[0][nf] = __builtin_amdgcn_mfma_f32_16x16x32_bf16(ua.s, b, acc[0][nf], 0, 0, 0);
        acc[1][nf] = __builtin_amdgcn_mfma_f32_16x16x32_bf16(ub.s, b, acc[1][nf], 0, 0, 0);
      }
    }
  };

  auto reduce_zs = [&]() {                        // 2-way-max bank pattern
#pragma unroll
    for (int mf = 0; mf < 2; ++mf)
#pragma unroll
      for (int nf = 0; nf < 4; ++nf)
#pragma unroll
        for (int e = 0; e < 4; ++e) {
          int row = mq * 32 + mf * 16 + lq * 4 + e;
          int col = (nf * 16 + l15) ^ (lq << 4);
          atomicAdd(&zs[row * 64 + col], acc[mf][nf][e]);
        }
  };

  auto st_reload = [&]() {                        // decoder weights (cell_W+cell_U)^T -> LDS
    const int r = tid & 63, slot = tid >> 6;
    const int n = (r >> 4) * 1024 + wgc * 16 + (r & 15);
    for (int i = 0; i < 4; ++i) {
      int kk = slot + 8 * i;                      // 0..31
      for (int j8 = 0; j8 < 4; ++j8) {
        short8 v;
#pragma unroll
        for (int j = 0; j < 8; ++j) {
          int k = kk * 32 + j8 * 8 + j;
          float f = celW[(size_t)k * 4096 + n] + celU[(size_t)k * 4096 + n];
          v[j] = bf16r(f);
        }
        uint32_t byte = ((uint32_t)(r * 1152 + kk * 32 + j8 * 8) * 2u) ^ (uint32_t)((r & 7) << 4);
        *(short8*)(smem + byte) = v;
      }
    }
  };

  // barrier with overlapped zs-zero + next-step x-part (+ optional weight reload)
  auto barrier_overlap = [&](int xt, bool reload) {
    asm volatile("s_waitcnt vmcnt(0)" ::: "memory");   // drain h stores
    __syncthreads();
    if (tid == 0)
      __hip_atomic_fetch_add(bar, 1u, __ATOMIC_RELAXED, __HIP_MEMORY_SCOPE_AGENT);
    ++syncno;
    { float* p = zs + tid * 8; float4v zz = {0.f,0.f,0.f,0.f};
      *(float4v*)p = zz; *(float4v*)(p + 4) = zz; }        // linear, conflict-free
#pragma unroll
    for (int mf = 0; mf < 2; ++mf)
#pragma unroll
      for (int nf = 0; nf < 4; ++nf) acc[mf][nf] = (float4v){0.f,0.f,0.f,0.f};
    if (xt >= 0) xpart(xt);
    if (reload) st_reload();
    if (tid == 0) {
      const unsigned tgt = syncno * 64u;
      while (mall_poll(bar) < tgt) __builtin_amdgcn_s_sleep(2);
    }
    __syncthreads();
  };

  auto epilogue = [&](bool dec, int td) {
    const float* zr = zs + erow * 64;
    float2 I = *(const float2*)(zr + (( 0 + 2 * ecp) ^ erot));
    float2 F = *(const float2*)(zr + ((16 + 2 * ecp) ^ erot));
    float2 G = *(const float2*)(zr + ((32 + 2 * ecp) ^ erot));
    float2 O = *(const float2*)(zr + ((48 + 2 * ecp) ^ erot));
    float i0, i1, f0, f1, g0, g1, o0, o1;
    if (!dec) { i0=I.x+bei0; i1=I.y+bei1; f0=F.x+bef0; f1=F.y+bef1;
                g0=G.x+beg0; g1=G.y+beg1; o0=O.x+beo0; o1=O.y+beo1; }
    else      { i0=I.x+bci0; i1=I.y+bci1; f0=F.x+bcf0; f1=F.y+bcf1;
                g0=G.x+bcg0; g1=G.y+bcg1; o0=O.x+bco0; o1=O.y+bco1; }
    cA = sig_(f0) * cA + sig_(i0) * tanh_(g0);
    cB = sig_(f1) * cB + sig_(i1) * tanh_(g1);
    float hA = sig_(o0) * tanh_(cA);
    float hB = sig_(o1) * tanh_(cB);
    unsigned hp = (unsigned)(unsigned short)bf16r(hA)
                | ((unsigned)(unsigned short)bf16r(hB) << 16);
    unsigned* h32 = (unsigned*)hb;
    size_t idx = (size_t)(cur ^ 1) * 131072 + (size_t)wgc * 2048 + (size_t)growg * 8 + ecp;
    AST(h32 + idx, hp);                            // coalesced
    if (dec) {
      float p = hA * dw0 + hB * dw1;
      p += __shfl_xor(p, 1); p += __shfl_xor(p, 2); p += __shfl_xor(p, 4);
      if (ecp == 0)
        atomicAdd(&out[(size_t)growg * 24 + td], p + (wgc == 0 ? db : 0.f));
    }
  };

  // ================= run =================
  barrier_overlap(0, false);                       // init barrier; overlap xpart(t=0)
  for (int t = 0; t < 512; ++t) {
    hpart(hb + (size_t)cur * HBUF_U64, 128);
    reduce_zs();
    __syncthreads();
    epilogue(false, 0);
    cur ^= 1;
    if (t < 511) barrier_overlap(t + 1, false);
    else         barrier_overlap(-1, true);        // overlap decoder weight reload
  }
  for (int td = 0; td < 24; ++td) {
    hpart(hb + (size_t)cur * HBUF_U64, 0);
    reduce_zs();
    __syncthreads();
    epilogue(true, td);
    cur ^= 1;
    if (td < 23) barrier_overlap(-1, false);
  }
}

extern "C" void kernel_launch(void* const* d_in, const int* in_sizes, int n_in,
                              void* d_out, int out_size, void* d_ws, size_t ws_size,
                              hipStream_t stream) {
  const float* x    = (const float*)d_in[0];
  const float* encW = (const float*)d_in[1];
  const float* encU = (const float*)d_in[2];
  const float* encB = (const float*)d_in[3];
  const float* celW = (const float*)d_in[4];
  const float* celU = (const float*)d_in[5];
  const float* celB = (const float*)d_in[6];
  const float* denW = (const float*)d_in[7];
  const float* denB = (const float*)d_in[8];
  float* out = (float*)d_out;

  if (ws_size < WS_NEED) return;                   // visible failure, no OOB

  u64*      hb  = (u64*)d_ws;
  unsigned* bar = (unsigned*)((char*)d_ws + HBUF_U64 * 2ull * 8ull);

  hipMemsetAsync(bar, 0, 512, stream);
  hipFuncSetAttribute((const void*)lstm_all,
                      hipFuncAttributeMaxDynamicSharedMemorySize, SMEM_BYTES);

  void* args[] = { (void*)&x, (void*)&encW, (void*)&encU, (void*)&encB,
                   (void*)&celW, (void*)&celU, (void*)&celB,
                   (void*)&denW, (void*)&denB,
                   (void*)&out, (void*)&hb, (void*)&bar };
  hipLaunchCooperativeKernel((void*)lstm_all, dim3(NWG), dim3(NTHR), args,
                             (unsigned)SMEM_BYTES, stream);
}

// Round 8
// 13953.833 us; speedup vs baseline: 1.6642x; 1.0007x over previous
//
#include <hip/hip_runtime.h>
#include <cstdint>

#define NWG  256
#define NTHR 512
#define HBUF_U64 65536ull                 // one h buffer: 256*1024 bf16 = 64K u64
#define WS_NEED  (HBUF_U64 * 2ull * 8ull + 1024ull)
#define BLDS_BYTES 147456                 // 64 rows * 1152 K * 2B (XOR-swizzled)
#define SMEM_BYTES (BLDS_BYTES + 16384)   // + zs 64*64 f32 = 160 KiB

typedef __attribute__((ext_vector_type(8))) short  short8;
typedef __attribute__((ext_vector_type(4))) float  float4v;
typedef unsigned long long u64;

#define ALD(p)    __hip_atomic_load((p), __ATOMIC_RELAXED, __HIP_MEMORY_SCOPE_AGENT)
#define AST(p, v) __hip_atomic_store((p), (v), __ATOMIC_RELAXED, __HIP_MEMORY_SCOPE_AGENT)

__device__ __forceinline__ short bf16r(float f) {
  union { float f; uint32_t u; } v; v.f = f;
  uint32_t r = (v.u + 0x7FFFu + ((v.u >> 16) & 1u)) >> 16;   // RNE
  return (short)(uint16_t)r;
}
__device__ __forceinline__ float sig_(float x)  { return 1.f / (1.f + __expf(-x)); }
__device__ __forceinline__ float tanh_(float x) {
  x = fminf(15.f, fmaxf(-15.f, x));
  float e = __expf(-2.f * x);
  return (1.f - e) / (1.f + e);
}

// MALL-direct 4B load / store (bypass L1/L2) — slot-barrier primitives
__device__ __forceinline__ unsigned mall_load(const unsigned* p) {
  unsigned v;
  asm volatile("global_load_dword %0, %1, off sc0 sc1\n\t"
               "s_waitcnt vmcnt(0)"
               : "=v"(v) : "v"((unsigned long long)p) : "memory");
  return v;
}
__device__ __forceinline__ void mall_store(unsigned* p, unsigned v) {
  asm volatile("global_store_dword %0, %1, off sc0 sc1"
               :: "v"((unsigned long long)p), "v"(v) : "memory");
}

__global__ void __launch_bounds__(NTHR, 1)
lstm_all(const float* __restrict__ x,
         const float* __restrict__ encW, const float* __restrict__ encU, const float* __restrict__ encB,
         const float* __restrict__ celW, const float* __restrict__ celU, const float* __restrict__ celB,
         const float* __restrict__ denW, const float* __restrict__ denB,
         float* __restrict__ out,
         u64* __restrict__ hb, unsigned* __restrict__ barp)
{
  extern __shared__ char smem[];                  // [B_lds 147456 | zs 16384]
  float* zs = (float*)(smem + BLDS_BYTES);

  const int tid = threadIdx.x, wg = blockIdx.x;
  // rowgroup -> XCD-pair locality (XCD = wg%8 model, validated by FETCH drop r6)
  const int wgr = (wg & 7) >> 1;                  // rowgroup on XCDs {2r, 2r+1}
  const int wgc = ((wg >> 3) << 1) | (wg & 1);    // colgroup 0..63 (bijective)
  unsigned* bar = barp + wgr * 64;                // 64 u32 slots per rowgroup (256B)
  unsigned syncno = 0;

  // ---- init: zero own h0 slab + out (rowgroup's slice) ----
  if (tid < 256)
    AST(hb + (size_t)wgc * 1024 + (size_t)wgr * 256 + tid, 0ull);
  if (wgc == 0)
    for (int i = tid; i < 768; i += NTHR)         // 64 rows * 24 f32 = 768 u64
      AST((u64*)out + (size_t)wgr * 768 + i, 0ull);

  // ---- encoder weight slice -> LDS (bf16, XOR-swizzled rows) ----
  {
    const int r = tid & 63, slot = tid >> 6;
    const int n = (r >> 4) * 1024 + wgc * 16 + (r & 15);
    for (int i = 0; i < 5; ++i) {
      int kk = slot + 8 * i;
      if (kk < 36) {
        for (int j8 = 0; j8 < 4; ++j8) {
          short8 v;
#pragma unroll
          for (int j = 0; j < 8; ++j) {
            int k = kk * 32 + j8 * 8 + j;
            float f = (k < 128) ? encW[(size_t)k * 4096 + n]
                                : encU[(size_t)(k - 128) * 4096 + n];
            v[j] = bf16r(f);
          }
          uint32_t byte = ((uint32_t)(r * 1152 + kk * 32 + j8 * 8) * 2u) ^ (uint32_t)((r & 7) << 4);
          *(short8*)(smem + byte) = v;
        }
      }
    }
  }

  // ---- ids ----
  const int lane = tid & 63, wv = tid >> 6;
  const int l15 = lane & 15, lq = lane >> 4;
  const int mq = wv & 1, ks = wv >> 1;            // wave -> (m-half, K-slice)
  uint32_t bbase[4], bmask[4];
#pragma unroll
  for (int nf = 0; nf < 4; ++nf) {
    int rB = nf * 16 + l15;
    bbase[nf] = (uint32_t)((rB * 1152 + lq * 8) * 2);
    bmask[nf] = (uint32_t)((rB & 7) << 4);
  }
  const int erow = tid >> 3, ecp = tid & 7;       // epilogue: row (local), col-pair
  const int gcol0 = wgc * 16 + 2 * ecp, gcol1 = gcol0 + 1;
  const int growg = wgr * 64 + erow;              // global row
  const int erot  = ((erow >> 2) & 3) << 4;       // zs col swizzle (matches lq<<4)
  const float bei0 = encB[gcol0], bei1 = encB[gcol1];
  const float bef0 = encB[1024 + gcol0], bef1 = encB[1024 + gcol1];
  const float beg0 = encB[2048 + gcol0], beg1 = encB[2048 + gcol1];
  const float beo0 = encB[3072 + gcol0], beo1 = encB[3072 + gcol1];
  const float bci0 = celB[gcol0], bci1 = celB[gcol1];
  const float bcf0 = celB[1024 + gcol0], bcf1 = celB[1024 + gcol1];
  const float bcg0 = celB[2048 + gcol0], bcg1 = celB[2048 + gcol1];
  const float bco0 = celB[3072 + gcol0], bco1 = celB[3072 + gcol1];
  const float dw0 = denW[gcol0], dw1 = denW[gcol1], db = denB[0];
  float cA = 0.f, cB = 0.f;
  int cur = 0;
  float4v acc[2][4];

  auto xpart = [&](int t) {                       // x_t @ W : wave ks does K-tile ks*32
    const int Kg = ks * 32;
    const float* xp0 = x + ((size_t)(wgr * 64 + mq * 32 + l15) * 512 + (size_t)t) * 128 + Kg + lq * 8;
    const float* xp1 = xp0 + (size_t)16 * 512 * 128;
    float4v u0 = *(const float4v*)xp0, u1 = *(const float4v*)(xp0 + 4);
    float4v w0 = *(const float4v*)xp1, w1 = *(const float4v*)(xp1 + 4);
    short8 a0, a1;
#pragma unroll
    for (int j = 0; j < 4; ++j) {
      a0[j] = bf16r(u0[j]); a0[4 + j] = bf16r(u1[j]);
      a1[j] = bf16r(w0[j]); a1[4 + j] = bf16r(w1[j]);
    }
#pragma unroll
    for (int nf = 0; nf < 4; ++nf) {
      short8 b = *(const short8*)(smem + ((bbase[nf] + 2u * (uint32_t)Kg) ^ bmask[nf]));
      acc[0][nf] = __builtin_amdgcn_mfma_f32_16x16x32_bf16(a0, b, acc[0][nf], 0, 0, 0);
      acc[1][nf] = __builtin_amdgcn_mfma_f32_16x16x32_bf16(a1, b, acc[1][nf], 0, 0, 0);
    }
  };

  // h @ U-slice: hoisted loads (registers), then MFMAs
  auto hpart = [&](const u64* hbase, int wk0) {
    const int rbase = wgr * 64 + mq * 32 + l15;
    u64 q0[8], q1[8], q2[8], q3[8];
#pragma unroll
    for (int kk = 0; kk < 8; ++kk) {
      const int kc = ks * 256 + kk * 32;
      const int c0 = kc + lq * 8;
      const size_t bidx = (size_t)(c0 >> 4) * 1024 + (size_t)rbase * 4 + (size_t)((c0 & 15) >> 2);
      q0[kk] = ALD(hbase + bidx);
      q1[kk] = ALD(hbase + bidx + 1);
      q2[kk] = ALD(hbase + bidx + 64);      // +16 rows
      q3[kk] = ALD(hbase + bidx + 65);
    }
#pragma unroll
    for (int kk = 0; kk < 8; ++kk) {
      const int kc = ks * 256 + kk * 32;
      union { u64 q[2]; short8 s; } ua, ub;
      ua.q[0] = q0[kk]; ua.q[1] = q1[kk];
      ub.q[0] = q2[kk]; ub.q[1] = q3[kk];
      const uint32_t Kw = (uint32_t)(wk0 + kc);
#pragma unroll
      for (int nf = 0; nf < 4; ++nf) {
        short8 b = *(const short8*)(smem + ((bbase[nf] + 2u * Kw) ^ bmask[nf]));
        acc[0][nf] = __builtin_amdgcn_mfma_f32_16x16x32_bf16(ua.s, b, acc[0][nf], 0, 0, 0);
        acc[1][nf] = __builtin_amdgcn_mfma_f32_16x16x32_bf16(ub.s, b, acc[1][nf], 0, 0, 0);
      }
    }
  };

  auto reduce_zs = [&]() {                        // 2-way-max bank pattern
#pragma unroll
    for (int mf = 0; mf < 2; ++mf)
#pragma unroll
      for (int nf = 0; nf < 4; ++nf)
#pragma unroll
        for (int e = 0; e < 4; ++e) {
          int row = mq * 32 + mf * 16 + lq * 4 + e;
          int col = (nf * 16 + l15) ^ (lq << 4);
          atomicAdd(&zs[row * 64 + col], acc[mf][nf][e]);
        }
  };

  auto st_reload = [&]() {                        // decoder weights (cell_W+cell_U)^T -> LDS
    const int r = tid & 63, slot = tid >> 6;
    const int n = (r >> 4) * 1024 + wgc * 16 + (r & 15);
    for (int i = 0; i < 4; ++i) {
      int kk = slot + 8 * i;                      // 0..31
      for (int j8 = 0; j8 < 4; ++j8) {
        short8 v;
#pragma unroll
        for (int j = 0; j < 8; ++j) {
          int k = kk * 32 + j8 * 8 + j;
          float f = celW[(size_t)k * 4096 + n] + celU[(size_t)k * 4096 + n];
          v[j] = bf16r(f);
        }
        uint32_t byte = ((uint32_t)(r * 1152 + kk * 32 + j8 * 8) * 2u) ^ (uint32_t)((r & 7) << 4);
        *(short8*)(smem + byte) = v;
      }
    }
  };

  // slot barrier (no RMW, no same-address contention) + overlapped work
  auto barrier_overlap = [&](int xt, bool reload) {
    asm volatile("s_waitcnt vmcnt(0)" ::: "memory");   // h stores visible at MALL
    __syncthreads();                                   // all threads drained
    ++syncno;
    if (tid == 0) mall_store(bar + wgc, syncno);       // own slot, parallel arrivals
    { float* p = zs + tid * 8; float4v zz = {0.f,0.f,0.f,0.f};
      *(float4v*)p = zz; *(float4v*)(p + 4) = zz; }    // linear, conflict-free
#pragma unroll
    for (int mf = 0; mf < 2; ++mf)
#pragma unroll
      for (int nf = 0; nf < 4; ++nf) acc[mf][nf] = (float4v){0.f,0.f,0.f,0.f};
    if (xt >= 0) xpart(xt);
    if (reload) st_reload();
    if (tid < 64) {                                    // wave 0: one slot per lane,
      while (mall_load(bar + tid) < syncno)            // coalesced 256B poll
        __builtin_amdgcn_s_sleep(4);
    }
    __syncthreads();
  };

  auto epilogue = [&](bool dec, int td) {
    const float* zr = zs + erow * 64;
    float2 I = *(const float2*)(zr + (( 0 + 2 * ecp) ^ erot));
    float2 F = *(const float2*)(zr + ((16 + 2 * ecp) ^ erot));
    float2 G = *(const float2*)(zr + ((32 + 2 * ecp) ^ erot));
    float2 O = *(const float2*)(zr + ((48 + 2 * ecp) ^ erot));
    float i0, i1, f0, f1, g0, g1, o0, o1;
    if (!dec) { i0=I.x+bei0; i1=I.y+bei1; f0=F.x+bef0; f1=F.y+bef1;
                g0=G.x+beg0; g1=G.y+beg1; o0=O.x+beo0; o1=O.y+beo1; }
    else      { i0=I.x+bci0; i1=I.y+bci1; f0=F.x+bcf0; f1=F.y+bcf1;
                g0=G.x+bcg0; g1=G.y+bcg1; o0=O.x+bco0; o1=O.y+bco1; }
    cA = sig_(f0) * cA + sig_(i0) * tanh_(g0);
    cB = sig_(f1) * cB + sig_(i1) * tanh_(g1);
    float hA = sig_(o0) * tanh_(cA);
    float hB = sig_(o1) * tanh_(cB);
    unsigned hp = (unsigned)(unsigned short)bf16r(hA)
                | ((unsigned)(unsigned short)bf16r(hB) << 16);
    unsigned* h32 = (unsigned*)hb;
    size_t idx = (size_t)(cur ^ 1) * 131072 + (size_t)wgc * 2048 + (size_t)growg * 8 + ecp;
    AST(h32 + idx, hp);                            // coalesced
    if (dec) {
      float p = hA * dw0 + hB * dw1;
      p += __shfl_xor(p, 1); p += __shfl_xor(p, 2); p += __shfl_xor(p, 4);
      if (ecp == 0)
        atomicAdd(&out[(size_t)growg * 24 + td], p + (wgc == 0 ? db : 0.f));
    }
  };

  // ================= run =================
  barrier_overlap(0, false);                       // init barrier; overlap xpart(t=0)
  for (int t = 0; t < 512; ++t) {
    hpart(hb + (size_t)cur * HBUF_U64, 128);
    reduce_zs();
    __syncthreads();
    epilogue(false, 0);
    cur ^= 1;
    if (t < 511) barrier_overlap(t + 1, false);
    else         barrier_overlap(-1, true);        // overlap decoder weight reload
  }
  for (int td = 0; td < 24; ++td) {
    hpart(hb + (size_t)cur * HBUF_U64, 0);
    reduce_zs();
    __syncthreads();
    epilogue(true, td);
    cur ^= 1;
    if (td < 23) barrier_overlap(-1, false);
  }
}

extern "C" void kernel_launch(void* const* d_in, const int* in_sizes, int n_in,
                              void* d_out, int out_size, void* d_ws, size_t ws_size,
                              hipStream_t stream) {
  const float* x    = (const float*)d_in[0];
  const float* encW = (const float*)d_in[1];
  const float* encU = (const float*)d_in[2];
  const float* encB = (const float*)d_in[3];
  const float* celW = (const float*)d_in[4];
  const float* celU = (const float*)d_in[5];
  const float* celB = (const float*)d_in[6];
  const float* denW = (const float*)d_in[7];
  const float* denB = (const float*)d_in[8];
  float* out = (float*)d_out;

  if (ws_size < WS_NEED) return;                   // visible failure, no OOB

  u64*      hb  = (u64*)d_ws;
  unsigned* bar = (unsigned*)((char*)d_ws + HBUF_U64 * 2ull * 8ull);

  hipMemsetAsync(bar, 0, 1024, stream);
  hipFuncSetAttribute((const void*)lstm_all,
                      hipFuncAttributeMaxDynamicSharedMemorySize, SMEM_BYTES);

  void* args[] = { (void*)&x, (void*)&encW, (void*)&encU, (void*)&encB,
                   (void*)&celW, (void*)&celU, (void*)&celB,
                   (void*)&denW, (void*)&denB,
                   (void*)&out, (void*)&hb, (void*)&bar };
  hipLaunchCooperativeKernel((void*)lstm_all, dim3(NWG), dim3(NTHR), args,
                             (unsigned)SMEM_BYTES, stream);
}